// Round 1
// 552.814 us; speedup vs baseline: 1.1842x; 1.1842x over previous
//
#include <hip/hip_runtime.h>
#include <stdint.h>

// GRU encoder B=512,T=512,H=256,IN=2 — R9: zero-shuffle gate layout.
// R8 base: W pinned in VGPRs (192 dwords), kt-outer MFMA, h16 LDS ping-pong.
// R9 change: A-row->batch map batch=(row>>2)&1 puts both batches x both col
// halves of each tile pair into REG 0 across the four 16-lane groups:
//   lanes  0-15: (b0, c)     = d_even[0]   lanes 16-31: (b1, c)     = d_even[0]
//   lanes 32-47: (b0, c+16)  = d_odd[0]    lanes 48-63: (b1, c+16)  = d_odd[0]
// -> uX = lane<32 ? d_even[0] : d_odd[0]; no __shfl, no lane<32 divergence,
// all 64 lanes compute exactly ONE gate slot (was: 32 lanes x 2 slots + 6
// ds_bpermute). MFMA count, W regs, A-read LDS pattern unchanged.

typedef _Float16 v8h  __attribute__((ext_vector_type(8)));
typedef float    f32x4 __attribute__((ext_vector_type(4)));

#define BB 512
#define TT 512
#define HH 256
#define NT 48    // 768/16 col tiles
#define KT 8     // 256/32 k tiles
#define HSTR 288 // padded h16 stride (halves): batch0/1 -> disjoint banks

// Wp4[(ct*KT + kt)*64 + lane] = 8 halves W_hh[16ct + (lane&15)][32kt + (lane>>4)*8 + j]
__global__ void prep_pack(const float* __restrict__ Whh, uint4* __restrict__ Wp4) {
    int n = blockIdx.x * blockDim.x + threadIdx.x;   // [0, 24576)
    int lane = n & 63;
    int kt = (n >> 6) & (KT - 1);
    int ct = n >> 9;
    int row = 16 * ct + (lane & 15);
    int k0  = 32 * kt + (lane >> 4) * 8;
    const float* src = Whh + (size_t)row * HH + k0;
    v8h v;
    #pragma unroll
    for (int j = 0; j < 8; ++j) v[j] = (_Float16)src[j];
    Wp4[n] = __builtin_bit_cast(uint4, v);
}

__device__ __forceinline__ float sigmoid_f(float x) {
    return __builtin_amdgcn_rcpf(1.f + __expf(-x));
}
__device__ __forceinline__ float tanh_f(float x) {
    x = fminf(fmaxf(x, -15.f), 15.f);
    float e = __expf(-2.f * x);
    return (1.f - e) * __builtin_amdgcn_rcpf(1.f + e);
}

__global__ void __launch_bounds__(512, 1)
gru_persist(const float* __restrict__ x,        // [B,T,2]
            const int* __restrict__ len,        // [B]
            const float* __restrict__ h0,       // [B,H]
            const float* __restrict__ Wih,      // [768,2]
            const float* __restrict__ bih,      // [768]
            const float* __restrict__ bhh,      // [768]
            const uint4* __restrict__ Wp4,      // MFMA-fragment-packed fp16 W_hh
            float* __restrict__ out)            // [B,H]
{
    __shared__ __align__(16) _Float16 h16[2][2][HSTR];  // [buf][batch][e]
    __shared__ float4 cst4[HH];   // cR,cZ,cN,dN
    __shared__ float4 wx4[HH];    // wR0,wR1,wZ0,wZ1
    __shared__ float2 wn2[HH];    // wN0,wN1

    const int tid  = threadIdx.x;
    const int lane = tid & 63;
    const int w    = tid >> 6;          // wave 0..7
    const int b0   = blockIdx.x * 2;

    // ---- W B-fragments for this wave's 6 tiles: 192 dwords in regs ----
    v8h wfr[6][KT];
    {
        const int cts[6] = {2*w, 2*w+1, 16+2*w, 16+2*w+1, 32+2*w, 32+2*w+1};
        #pragma unroll
        for (int c = 0; c < 6; ++c)
            #pragma unroll
            for (int kt = 0; kt < KT; ++kt)
                wfr[c][kt] = __builtin_bit_cast(v8h, Wp4[(cts[c] * KT + kt) * 64 + lane]);
    }
    #pragma unroll
    for (int c = 0; c < 6; ++c)
        #pragma unroll
        for (int kt = 0; kt < KT; ++kt)
            asm volatile("" : "+v"(wfr[c][kt]));   // reg-resident, not remat

    // ---- per-element gate constants into LDS ----
    if (tid < HH) {
        const int e2 = tid;
        cst4[e2] = float4{bih[e2] + bhh[e2], bih[HH + e2] + bhh[HH + e2],
                          bih[2 * HH + e2], bhh[2 * HH + e2]};
        wx4[e2] = float4{Wih[2 * e2], Wih[2 * e2 + 1],
                         Wih[2 * (HH + e2)], Wih[2 * (HH + e2) + 1]};
        wn2[e2] = float2{Wih[2 * (2 * HH + e2)], Wih[2 * (2 * HH + e2) + 1]};
    }

    // ---- gate-slot mapping: one slot per lane ----
    // batch = (lane>>4)&1 ; e = 32w + (lane&15) + 16*(lane>>5)
    const int batch = (lane >> 4) & 1;
    const int e = 32 * w + (lane & 15) + ((lane >> 5) << 4);

    float hp = h0[(size_t)(b0 + batch) * HH + e];
    h16[0][batch][e] = (_Float16)hp;     // every (batch,e) covered exactly once

    const int l0 = len[b0], l1 = len[b0 + 1];
    const int lm  = l0 > l1 ? l0 : l1;   // uniform loop bound
    const int lmy = batch ? l1 : l0;     // per-lane length
    const float2* xp = (const float2*)x + (size_t)(b0 + batch) * TT;
    float* op = out + (size_t)(b0 + batch) * HH + e;

    // A-frag: row m = lane&15 -> batch (m>>2)&1, k chunk = (lane>>4)*8.
    // 8 distinct 16B addrs/wave (2 batch x 4 kchunk), conflict-free as before.
    const _Float16* abase = &h16[0][(lane >> 2) & 1][(lane >> 4) * 8];

    __syncthreads();

    #pragma unroll 1
    for (int s = 0; s < lm; ++s) {
        const float2 xv = xp[s];

        const _Float16* ap = abase + (s & 1) * (2 * HSTR);  // h16 ping-pong
        f32x4 d0 = {0.f,0.f,0.f,0.f}, d1 = {0.f,0.f,0.f,0.f}, d2 = {0.f,0.f,0.f,0.f};
        f32x4 d3 = {0.f,0.f,0.f,0.f}, d4 = {0.f,0.f,0.f,0.f}, d5 = {0.f,0.f,0.f,0.f};
        #pragma unroll
        for (int kt = 0; kt < KT; ++kt) {     // kt-outer: one A-frag live
            const v8h a = *(const v8h*)(ap + kt * 32);   // ds_read_b128 broadcast
            d0 = __builtin_amdgcn_mfma_f32_16x16x32_f16(a, wfr[0][kt], d0, 0, 0, 0);
            d1 = __builtin_amdgcn_mfma_f32_16x16x32_f16(a, wfr[1][kt], d1, 0, 0, 0);
            d2 = __builtin_amdgcn_mfma_f32_16x16x32_f16(a, wfr[2][kt], d2, 0, 0, 0);
            d3 = __builtin_amdgcn_mfma_f32_16x16x32_f16(a, wfr[3][kt], d3, 0, 0, 0);
            d4 = __builtin_amdgcn_mfma_f32_16x16x32_f16(a, wfr[4][kt], d4, 0, 0, 0);
            d5 = __builtin_amdgcn_mfma_f32_16x16x32_f16(a, wfr[5][kt], d5, 0, 0, 0);
        }

        // reg 0 spans D-rows {0,4,8,12} over the four lane groups:
        // even tile reg0 = (b0,c)|(b1,c) on lanes 0-31; odd tile reg0 =
        // (b0,c+16)|(b1,c+16) on lanes 32-63. One select per gate, no shfl.
        const bool hi = lane >= 32;
        const float uR = hi ? d1[0] : d0[0];
        const float uZ = hi ? d3[0] : d2[0];
        const float uN = hi ? d5[0] : d4[0];

        const float4 cc  = cst4[e];
        const float4 wxv = wx4[e];
        const float2 wnv = wn2[e];
        const float r = sigmoid_f(uR + fmaf(xv.x, wxv.x, fmaf(xv.y, wxv.y, cc.x)));
        const float z = sigmoid_f(uZ + fmaf(xv.x, wxv.z, fmaf(xv.y, wxv.w, cc.y)));
        const float n = tanh_f(fmaf(xv.x, wnv.x, fmaf(xv.y, wnv.y, cc.z)) + r * (uN + cc.w));
        float hn = fmaf(z, hp - n, n);
        hn = (s < lmy) ? hn : hp;            // freeze finished batch
        h16[(s & 1) ^ 1][batch][e] = (_Float16)hn;
        hp = hn;
        if (s == lmy - 1) *op = hn;
        __syncthreads();   // new h16 buffer visible for next step's A reads
    }
}

extern "C" void kernel_launch(void* const* d_in, const int* in_sizes, int n_in,
                              void* d_out, int out_size, void* d_ws, size_t ws_size,
                              hipStream_t stream) {
    const float* x    = (const float*)d_in[0];
    const int*   lenp = (const int*)d_in[1];
    const float* h0   = (const float*)d_in[2];
    const float* Wih  = (const float*)d_in[3];
    const float* Whh  = (const float*)d_in[4];
    const float* bih  = (const float*)d_in[5];
    const float* bhh  = (const float*)d_in[6];
    float* out = (float*)d_out;

    uint4* Wp4 = (uint4*)d_ws;   // 384 KB scratch

    prep_pack<<<NT * KT * 64 / 256, 256, 0, stream>>>(Whh, Wp4);
    gru_persist<<<BB / 2, 512, 0, stream>>>(x, lenp, h0, Wih, bih, bhh, Wp4, out);
}

// Round 2
// 532.426 us; speedup vs baseline: 1.2295x; 1.0383x over previous
//
#include <hip/hip_runtime.h>
#include <stdint.h>

// GRU encoder B=512,T=512,H=256,IN=2 — R10: gate/MFMA phase overlap.
// R9 base: zero-shuffle gate layout (batch=(row>>2)&1 A-map; one gate slot
// per lane; no ds_bpermute). R10 changes:
//  1. Phase-split MFMAs: {R,N tiles: d0,d1,d4,d5} first, then the long
//     r->tanh(n) dependent chain, then {Z tiles: d2,d3}. The Z-tile pipe
//     time (~16 MFMA ~ 310 cyc/SIMD) hides the transcendental chain that
//     previously sat entirely after the last MFMA (lockstep waves -> pipe
//     idle during gate tail). Tail shrinks to z-sigmoid + hn + write.
//  2. Gate constants (bih/bhh/Wih per-element) hoisted to registers —
//     VGPR headroom is large (120); LDS staging arrays dropped.
//  3. Next-step x prefetch (L2 latency off the critical path).
// MFMA count, W-in-VGPR pinning, h16 ping-pong + 1 barrier/step unchanged.

typedef _Float16 v8h  __attribute__((ext_vector_type(8)));
typedef float    f32x4 __attribute__((ext_vector_type(4)));

#define BB 512
#define TT 512
#define HH 256
#define NT 48    // 768/16 col tiles
#define KT 8     // 256/32 k tiles
#define HSTR 288 // padded h16 stride (halves): batch0/1 -> disjoint banks

// Wp4[(ct*KT + kt)*64 + lane] = 8 halves W_hh[16ct + (lane&15)][32kt + (lane>>4)*8 + j]
__global__ void prep_pack(const float* __restrict__ Whh, uint4* __restrict__ Wp4) {
    int n = blockIdx.x * blockDim.x + threadIdx.x;   // [0, 24576)
    int lane = n & 63;
    int kt = (n >> 6) & (KT - 1);
    int ct = n >> 9;
    int row = 16 * ct + (lane & 15);
    int k0  = 32 * kt + (lane >> 4) * 8;
    const float* src = Whh + (size_t)row * HH + k0;
    v8h v;
    #pragma unroll
    for (int j = 0; j < 8; ++j) v[j] = (_Float16)src[j];
    Wp4[n] = __builtin_bit_cast(uint4, v);
}

__device__ __forceinline__ float sigmoid_f(float x) {
    return __builtin_amdgcn_rcpf(1.f + __expf(-x));
}
__device__ __forceinline__ float tanh_f(float x) {
    x = fminf(fmaxf(x, -15.f), 15.f);
    float e = __expf(-2.f * x);
    return (1.f - e) * __builtin_amdgcn_rcpf(1.f + e);
}

__global__ void __launch_bounds__(512, 1)
gru_persist(const float* __restrict__ x,        // [B,T,2]
            const int* __restrict__ len,        // [B]
            const float* __restrict__ h0,       // [B,H]
            const float* __restrict__ Wih,      // [768,2]
            const float* __restrict__ bih,      // [768]
            const float* __restrict__ bhh,      // [768]
            const uint4* __restrict__ Wp4,      // MFMA-fragment-packed fp16 W_hh
            float* __restrict__ out)            // [B,H]
{
    __shared__ __align__(16) _Float16 h16[2][2][HSTR];  // [buf][batch][e]

    const int tid  = threadIdx.x;
    const int lane = tid & 63;
    const int w    = tid >> 6;          // wave 0..7
    const int b0   = blockIdx.x * 2;

    // ---- W B-fragments for this wave's 6 tiles: 192 dwords in regs ----
    v8h wfr[6][KT];
    {
        const int cts[6] = {2*w, 2*w+1, 16+2*w, 16+2*w+1, 32+2*w, 32+2*w+1};
        #pragma unroll
        for (int c = 0; c < 6; ++c)
            #pragma unroll
            for (int kt = 0; kt < KT; ++kt)
                wfr[c][kt] = __builtin_bit_cast(v8h, Wp4[(cts[c] * KT + kt) * 64 + lane]);
    }
    #pragma unroll
    for (int c = 0; c < 6; ++c)
        #pragma unroll
        for (int kt = 0; kt < KT; ++kt)
            asm volatile("" : "+v"(wfr[c][kt]));   // reg-resident, not remat

    // ---- gate-slot mapping: one slot per lane ----
    // batch = (lane>>4)&1 ; e = 32w + (lane&15) + 16*(lane>>5)
    const int batch = (lane >> 4) & 1;
    const int e = 32 * w + (lane & 15) + ((lane >> 5) << 4);

    // ---- loop-invariant gate constants in registers (R10: was LDS) ----
    const float ccx = bih[e] + bhh[e];                     // r bias
    const float ccy = bih[HH + e] + bhh[HH + e];           // z bias
    const float ccz = bih[2 * HH + e];                     // n input bias
    const float ccw = bhh[2 * HH + e];                     // n hidden bias
    const float wxr0 = Wih[2 * e],            wxr1 = Wih[2 * e + 1];
    const float wxz0 = Wih[2 * (HH + e)],     wxz1 = Wih[2 * (HH + e) + 1];
    const float wxn0 = Wih[2 * (2 * HH + e)], wxn1 = Wih[2 * (2 * HH + e) + 1];

    float hp = h0[(size_t)(b0 + batch) * HH + e];
    h16[0][batch][e] = (_Float16)hp;     // every (batch,e) covered exactly once

    const int l0 = len[b0], l1 = len[b0 + 1];
    const int lm  = l0 > l1 ? l0 : l1;   // uniform loop bound
    const int lmy = batch ? l1 : l0;     // per-lane length
    const float2* xp = (const float2*)x + (size_t)(b0 + batch) * TT;
    float* op = out + (size_t)(b0 + batch) * HH + e;

    // A-frag: row m = lane&15 -> batch (m>>2)&1, k chunk = (lane>>4)*8.
    // 8 distinct 16B addrs/wave (2 batch x 4 kchunk), conflict-free.
    const _Float16* abase = &h16[0][(lane >> 2) & 1][(lane >> 4) * 8];

    __syncthreads();

    float2 xv = xp[0];
    #pragma unroll 1
    for (int s = 0; s < lm; ++s) {
        const int sn = (s + 1 < TT) ? s + 1 : s;
        const float2 xvn = xp[sn];                 // prefetch next step's x

        // input-projection terms (independent of MFMA chain)
        const float gR = fmaf(xv.x, wxr0, fmaf(xv.y, wxr1, ccx));
        const float gZ = fmaf(xv.x, wxz0, fmaf(xv.y, wxz1, ccy));
        const float gN = fmaf(xv.x, wxn0, fmaf(xv.y, wxn1, ccz));

        const _Float16* ap = abase + (s & 1) * (2 * HSTR);  // h16 ping-pong
        f32x4 d0 = {0.f,0.f,0.f,0.f}, d1 = {0.f,0.f,0.f,0.f};
        f32x4 d2 = {0.f,0.f,0.f,0.f}, d3 = {0.f,0.f,0.f,0.f};
        f32x4 d4 = {0.f,0.f,0.f,0.f}, d5 = {0.f,0.f,0.f,0.f};

        // ---- phase A: R tiles (d0,d1) + N tiles (d4,d5) ----
        #pragma unroll
        for (int kt = 0; kt < KT; ++kt) {
            const v8h a = *(const v8h*)(ap + kt * 32);   // ds_read_b128 broadcast
            d0 = __builtin_amdgcn_mfma_f32_16x16x32_f16(a, wfr[0][kt], d0, 0, 0, 0);
            d1 = __builtin_amdgcn_mfma_f32_16x16x32_f16(a, wfr[1][kt], d1, 0, 0, 0);
            d4 = __builtin_amdgcn_mfma_f32_16x16x32_f16(a, wfr[4][kt], d4, 0, 0, 0);
            d5 = __builtin_amdgcn_mfma_f32_16x16x32_f16(a, wfr[5][kt], d5, 0, 0, 0);
        }

        // long dependent chain: r -> n (two chained transcendentals).
        // Issued before phase B so its latency hides under Z-tile MFMAs.
        const bool hi = lane >= 32;
        const float uR = hi ? d1[0] : d0[0];
        const float uN = hi ? d5[0] : d4[0];
        const float r = sigmoid_f(uR + gR);
        const float n = tanh_f(gN + r * (uN + ccw));

        // ---- phase B: Z tiles (d2,d3) — independent of r/n chain ----
        #pragma unroll
        for (int kt = 0; kt < KT; ++kt) {
            const v8h a = *(const v8h*)(ap + kt * 32);
            d2 = __builtin_amdgcn_mfma_f32_16x16x32_f16(a, wfr[2][kt], d2, 0, 0, 0);
            d3 = __builtin_amdgcn_mfma_f32_16x16x32_f16(a, wfr[3][kt], d3, 0, 0, 0);
        }

        const float uZ = hi ? d3[0] : d2[0];
        const float z = sigmoid_f(uZ + gZ);
        float hn = fmaf(z, hp - n, n);
        hn = (s < lmy) ? hn : hp;            // freeze finished batch
        h16[(s & 1) ^ 1][batch][e] = (_Float16)hn;
        hp = hn;
        if (s == lmy - 1) *op = hn;
        xv = xvn;
        __syncthreads();   // new h16 buffer visible for next step's A reads
    }
}

extern "C" void kernel_launch(void* const* d_in, const int* in_sizes, int n_in,
                              void* d_out, int out_size, void* d_ws, size_t ws_size,
                              hipStream_t stream) {
    const float* x    = (const float*)d_in[0];
    const int*   lenp = (const int*)d_in[1];
    const float* h0   = (const float*)d_in[2];
    const float* Wih  = (const float*)d_in[3];
    const float* Whh  = (const float*)d_in[4];
    const float* bih  = (const float*)d_in[5];
    const float* bhh  = (const float*)d_in[6];
    float* out = (float*)d_out;

    uint4* Wp4 = (uint4*)d_ws;   // 384 KB scratch

    prep_pack<<<NT * KT * 64 / 256, 256, 0, stream>>>(Whh, Wp4);
    gru_persist<<<BB / 2, 512, 0, stream>>>(x, lenp, h0, Wih, bih, bhh, Wp4, out);
}